// Round 6
// baseline (127.159 us; speedup 1.0000x reference)
//
#include <hip/hip_runtime.h>
#include <hip/hip_bf16.h>
#include <math.h>

#define ENC 512
#define ATT 256
#define NN 1024
#define PP 1024

typedef __attribute__((ext_vector_type(8))) __bf16 bf16x8;
typedef __attribute__((ext_vector_type(4))) float floatx4;
typedef __attribute__((ext_vector_type(2))) float floatx2;

union LdsVec { uint4 u; bf16x8 v; };

// packed fp32->bf16 RNE via v_cvt_pk_bf16_f32 (gfx950)
__device__ __forceinline__ unsigned cvt_pk(float lo, float hi) {
    union { __hip_bfloat162 h; unsigned u; } x;
    x.h = __float22bfloat162_rn(float2{lo, hi});
    return x.u;
}
__device__ __forceinline__ uint4 cvt8(float4 f0, float4 f1) {
    uint4 r;
    r.x = cvt_pk(f0.x, f0.y); r.y = cvt_pk(f0.z, f0.w);
    r.z = cvt_pk(f1.x, f1.y); r.w = cvt_pk(f1.z, f1.w);
    return r;
}
// one packed u32 (2 bf16) -> 2 fp32
__device__ __forceinline__ float2 bfpair(unsigned w) {
    union { unsigned u; float f; } lo, hi;
    lo.u = w << 16; hi.u = w & 0xffff0000u;
    return float2{lo.f, hi.f};
}

// LDS tile: [rows][32 k] bf16, row stride 64B; 16B chunks XOR-swizzled.
__device__ __forceinline__ int tile_off(int row, int k) {
    return row * 32 + ((((k >> 3) ^ ((row >> 1) & 3)) & 3) << 3) + (k & 7);
}

// ---------------------------------------------------------------------------
// Kernel 1 (grid 4 x 16 x 4):
//  z=0..2: uT/v1T/v2T = bf16 transposed [a=256][m=1024] GEMM outputs.
//  z=3: ET = bf16 transpose of encoder (E^T [512][1024]) for mfma_awe.
// GEMM: 64x64 tile, BK=32, 16x16x32 bf16 MFMA, double-buffered LDS.
// ---------------------------------------------------------------------------
__global__ __launch_bounds__(256) void mfma_uv(
    const float* __restrict__ E,  const float* __restrict__ We, const float* __restrict__ be,
    const float* __restrict__ D,  const float* __restrict__ Wt, const float* __restrict__ bt,
    const float* __restrict__ Lg, const float* __restrict__ Wl, const float* __restrict__ bl,
    unsigned short* __restrict__ uT, unsigned short* __restrict__ v1T,
    unsigned short* __restrict__ v2T, unsigned short* __restrict__ ET)
{
    const int tid = threadIdx.x;

    if (blockIdx.z == 3) {
        // ---- E^T bf16 producer: two 64x64 tiles per block ----
        __shared__ unsigned short T[64][72];
        const int k0 = blockIdx.y * 64;
        const int kr = tid >> 2, nc = (tid & 3) * 16;
        const int nr = tid >> 2, kc = (tid & 3) * 16;
        #pragma unroll
        for (int t = 0; t < 2; ++t) {
            const int n0 = (blockIdx.x * 2 + t) * 64;
            const float* ep = E + (size_t)(k0 + kr) * ENC + n0 + nc;
            float4 a = *(const float4*)(ep + 0),  b = *(const float4*)(ep + 4);
            float4 c = *(const float4*)(ep + 8),  d = *(const float4*)(ep + 12);
            if (t) __syncthreads();
            *(uint4*)&T[kr][nc]     = cvt8(a, b);
            *(uint4*)&T[kr][nc + 8] = cvt8(c, d);
            __syncthreads();
            unsigned short tmp[16];
            #pragma unroll
            for (int i = 0; i < 16; ++i) tmp[i] = T[kc + i][nr];
            unsigned short* op = ET + (size_t)(n0 + nr) * PP + k0 + kc;
            *(uint4*)(op)     = *(uint4*)&tmp[0];
            *(uint4*)(op + 8) = *(uint4*)&tmp[8];
        }
        return;
    }

    __shared__ __align__(16) unsigned short As[2][64 * 32];
    __shared__ __align__(16) unsigned short Bs[2][64 * 32];
    const int K = 512;

    const float *A, *B, *bias; unsigned short* out;
    if      (blockIdx.z == 0) { A = E;  B = We; bias = be; out = uT;  }
    else if (blockIdx.z == 1) { A = D;  B = Wt; bias = bt; out = v1T; }
    else                      { A = Lg; B = Wl; bias = bl; out = v2T; }

    const int m0 = blockIdx.y * 64, n0 = blockIdx.x * 64;
    const int wv = tid >> 6, lm = tid & 15, lq = (tid >> 4) & 3;
    const int mb = (wv & 1) * 32, nb = (wv >> 1) * 32;
    const int a0o = tile_off(mb + lm,      lq * 8);
    const int a1o = tile_off(mb + 16 + lm, lq * 8);
    const int b0o = tile_off(nb + lm,      lq * 8);
    const int b1o = tile_off(nb + 16 + lm, lq * 8);

    const int row = tid >> 2, kseg = tid & 3;
    const int soff = tile_off(row, kseg * 8);
    const float* Ap = A + (size_t)(m0 + row) * K + kseg * 8;
    const float* Bp = B + (size_t)(n0 + row) * K + kseg * 8;

    floatx4 acc[2][2];
    const floatx4 zero = {0.f, 0.f, 0.f, 0.f};
    acc[0][0] = zero; acc[0][1] = zero; acc[1][0] = zero; acc[1][1] = zero;

    float4 pa0 = *(const float4*)(Ap), pa1 = *(const float4*)(Ap + 4);
    float4 pb0 = *(const float4*)(Bp), pb1 = *(const float4*)(Bp + 4);

    for (int k0 = 0; k0 < K; k0 += 32) {
        const int buf = (k0 >> 5) & 1;
        *(uint4*)&As[buf][soff] = cvt8(pa0, pa1);
        *(uint4*)&Bs[buf][soff] = cvt8(pb0, pb1);
        __syncthreads();
        if (k0 + 32 < K) {
            pa0 = *(const float4*)(Ap + k0 + 32); pa1 = *(const float4*)(Ap + k0 + 36);
            pb0 = *(const float4*)(Bp + k0 + 32); pb1 = *(const float4*)(Bp + k0 + 36);
        }
        LdsVec fa0, fa1, fb0, fb1;
        fa0.u = *(const uint4*)&As[buf][a0o];
        fa1.u = *(const uint4*)&As[buf][a1o];
        fb0.u = *(const uint4*)&Bs[buf][b0o];
        fb1.u = *(const uint4*)&Bs[buf][b1o];
        acc[0][0] = __builtin_amdgcn_mfma_f32_16x16x32_bf16(fa0.v, fb0.v, acc[0][0], 0, 0, 0);
        acc[0][1] = __builtin_amdgcn_mfma_f32_16x16x32_bf16(fa0.v, fb1.v, acc[0][1], 0, 0, 0);
        acc[1][0] = __builtin_amdgcn_mfma_f32_16x16x32_bf16(fa1.v, fb0.v, acc[1][0], 0, 0, 0);
        acc[1][1] = __builtin_amdgcn_mfma_f32_16x16x32_bf16(fa1.v, fb1.v, acc[1][1], 0, 0, 0);
    }

    // transposed bf16 epilogue: out[a][m]
    #pragma unroll
    for (int s = 0; s < 2; ++s) {
        const int col = n0 + nb + s * 16 + lm;          // a-dim
        const float bsum = bias[col];
        #pragma unroll
        for (int t = 0; t < 2; ++t) {
            const int mbase = m0 + mb + t * 16 + lq * 4;
            uint2 o;
            o.x = cvt_pk(acc[t][s][0] + bsum, acc[t][s][1] + bsum);
            o.y = cvt_pk(acc[t][s][2] + bsum, acc[t][s][3] + bsum);
            *(uint2*)&out[(size_t)col * NN + mbase] = o;
        }
    }
}

// ---------------------------------------------------------------------------
// Kernel 2: att[n,p] = sum_a relu(uT[a,p] + v1T[a,n] + v2T[a,n]) * Wf[a]
// Block tile 128p x 64n, thread 8p x 4n (p-set {tx*4, 64+tx*4} keeps LDS
// compute reads at 16B stride -> conflict-free).  z halves a -> 256 blocks.
// ---------------------------------------------------------------------------
__global__ __launch_bounds__(256) void att_fused(
    const unsigned short* __restrict__ uT, const unsigned short* __restrict__ v1T,
    const unsigned short* __restrict__ v2T,
    const float* __restrict__ Wf, float* __restrict__ att_part)
{
    __shared__ float us[32][132];   // stride 132 spreads staging-write banks
    __shared__ float vs[32][68];
    __shared__ float wfs[128];
    const int tid = threadIdx.x;
    const int z = blockIdx.z;
    if (tid < 128) wfs[tid] = Wf[z * 128 + tid];
    const int p0 = blockIdx.x * 128, n0 = blockIdx.y * 64;
    const int arow = tid >> 3, t8 = tid & 7;
    const int pcol = t8 * 16, ncol = t8 * 8;
    const int tx = tid & 15, ty = tid >> 4;

    floatx2 acc[4][4];              // [j: n][0,1 = p0..3 pairs; 2,3 = p64..67]
    const floatx2 z2 = {0.f, 0.f};
    #pragma unroll
    for (int j = 0; j < 4; ++j)
        #pragma unroll
        for (int h = 0; h < 4; ++h) acc[j][h] = z2;

    const int abase = z * 128;
    for (int ac = 0; ac < 128; ac += 32) {
        __syncthreads();
        {
            const size_t arow_g = (size_t)(abase + ac + arow) * NN;
            const unsigned short* up = uT + arow_g + p0 + pcol;
            uint4 ua = *(const uint4*)up;
            uint4 ub = *(const uint4*)(up + 8);
            float* ud = &us[arow][pcol];
            float2 c;
            c = bfpair(ua.x); ud[0] = c.x; ud[1] = c.y;
            c = bfpair(ua.y); ud[2] = c.x; ud[3] = c.y;
            c = bfpair(ua.z); ud[4] = c.x; ud[5] = c.y;
            c = bfpair(ua.w); ud[6] = c.x; ud[7] = c.y;
            c = bfpair(ub.x); ud[8] = c.x; ud[9] = c.y;
            c = bfpair(ub.y); ud[10] = c.x; ud[11] = c.y;
            c = bfpair(ub.z); ud[12] = c.x; ud[13] = c.y;
            c = bfpair(ub.w); ud[14] = c.x; ud[15] = c.y;
            uint4 va = *(const uint4*)(v1T + arow_g + n0 + ncol);
            uint4 vb = *(const uint4*)(v2T + arow_g + n0 + ncol);
            float* vd = &vs[arow][ncol];
            float2 a0, b0;
            a0 = bfpair(va.x); b0 = bfpair(vb.x); vd[0] = a0.x + b0.x; vd[1] = a0.y + b0.y;
            a0 = bfpair(va.y); b0 = bfpair(vb.y); vd[2] = a0.x + b0.x; vd[3] = a0.y + b0.y;
            a0 = bfpair(va.z); b0 = bfpair(vb.z); vd[4] = a0.x + b0.x; vd[5] = a0.y + b0.y;
            a0 = bfpair(va.w); b0 = bfpair(vb.w); vd[6] = a0.x + b0.x; vd[7] = a0.y + b0.y;
        }
        __syncthreads();
        #pragma unroll
        for (int a = 0; a < 32; ++a) {
            float4 u0 = *(const float4*)&us[a][tx * 4];
            float4 u1 = *(const float4*)&us[a][tx * 4 + 64];
            float4 v4 = *(const float4*)&vs[a][ty * 4];
            const float w = wfs[ac + a];
            floatx2 u00 = {u0.x, u0.y}, u01 = {u0.z, u0.w};
            floatx2 u10 = {u1.x, u1.y}, u11 = {u1.z, u1.w};
            const float vv[4] = {v4.x, v4.y, v4.z, v4.w};
            #pragma unroll
            for (int j = 0; j < 4; ++j) {
                floatx2 t0 = __builtin_elementwise_max(u00 + vv[j], z2);
                floatx2 t1 = __builtin_elementwise_max(u01 + vv[j], z2);
                floatx2 t2 = __builtin_elementwise_max(u10 + vv[j], z2);
                floatx2 t3 = __builtin_elementwise_max(u11 + vv[j], z2);
                acc[j][0] = t0 * w + acc[j][0];
                acc[j][1] = t1 * w + acc[j][1];
                acc[j][2] = t2 * w + acc[j][2];
                acc[j][3] = t3 * w + acc[j][3];
            }
        }
    }

    float* outp = att_part + (size_t)z * NN * PP;
    #pragma unroll
    for (int j = 0; j < 4; ++j) {
        float* rowp = &outp[(size_t)(n0 + ty * 4 + j) * PP + p0];
        float4 o;
        o.x = acc[j][0].x; o.y = acc[j][0].y; o.z = acc[j][1].x; o.w = acc[j][1].y;
        *(float4*)&rowp[tx * 4] = o;
        o.x = acc[j][2].x; o.y = acc[j][2].y; o.z = acc[j][3].x; o.w = acc[j][3].y;
        *(float4*)&rowp[tx * 4 + 64] = o;
    }
}

// ---------------------------------------------------------------------------
// Kernel 3: softmax over p of (att_part0 + att_part1); fp32 alpha to d_out,
// bf16 alpha to ws.  Wave-per-row, no barriers.
// ---------------------------------------------------------------------------
__global__ __launch_bounds__(256) void softmax_rows(
    const float* __restrict__ att_part, float* __restrict__ alpha,
    unsigned short* __restrict__ alpha_bf)
{
    const int wv = threadIdx.x >> 6, lane = threadIdx.x & 63;
    const int n = blockIdx.x * 4 + wv;
    const float* r0 = att_part + (size_t)n * PP;
    const float* r1 = att_part + (size_t)NN * PP + (size_t)n * PP;

    float4 x[4];
    #pragma unroll
    for (int i = 0; i < 4; ++i) {
        float4 a = *(const float4*)&r0[i * 256 + lane * 4];
        float4 b = *(const float4*)&r1[i * 256 + lane * 4];
        x[i].x = a.x + b.x; x[i].y = a.y + b.y; x[i].z = a.z + b.z; x[i].w = a.w + b.w;
    }

    float m = -1e30f;
    #pragma unroll
    for (int i = 0; i < 4; ++i)
        m = fmaxf(m, fmaxf(fmaxf(x[i].x, x[i].y), fmaxf(x[i].z, x[i].w)));
    #pragma unroll
    for (int off = 32; off > 0; off >>= 1) m = fmaxf(m, __shfl_xor(m, off, 64));

    float s = 0.f;
    #pragma unroll
    for (int i = 0; i < 4; ++i) {
        x[i].x = __expf(x[i].x - m); x[i].y = __expf(x[i].y - m);
        x[i].z = __expf(x[i].z - m); x[i].w = __expf(x[i].w - m);
        s += x[i].x + x[i].y + x[i].z + x[i].w;
    }
    #pragma unroll
    for (int off = 32; off > 0; off >>= 1) s += __shfl_xor(s, off, 64);
    const float inv = 1.0f / s;

    float* ar = alpha + (size_t)n * PP;
    unsigned short* br = alpha_bf + (size_t)n * PP;
    #pragma unroll
    for (int i = 0; i < 4; ++i) {
        x[i].x *= inv; x[i].y *= inv; x[i].z *= inv; x[i].w *= inv;
        *(float4*)&ar[i * 256 + lane * 4] = x[i];
        uint2 pk;
        pk.x = cvt_pk(x[i].x, x[i].y);
        pk.y = cvt_pk(x[i].z, x[i].w);
        *(uint2*)&br[i * 256 + lane * 4] = pk;
    }
}

// ---------------------------------------------------------------------------
// Kernel 4: awe = alpha @ E, bf16 operands (alpha_bf, ET).
// Tile 32m x 64n, BK=32, 256 blocks, pure copy staging.
// ---------------------------------------------------------------------------
__global__ __launch_bounds__(256) void mfma_awe(
    const unsigned short* __restrict__ alpha_bf,
    const unsigned short* __restrict__ ET, float* __restrict__ awe)
{
    __shared__ __align__(16) unsigned short As[2][32 * 32];
    __shared__ __align__(16) unsigned short Bs[2][64 * 32];
    const int tid = threadIdx.x;
    const int K = PP;
    const int m0 = blockIdx.y * 32, n0 = blockIdx.x * 64;
    const int wv = tid >> 6, lm = tid & 15, lq = (tid >> 4) & 3;
    const int mw = (wv & 1) * 16, nw = (wv >> 1) * 32;
    const int a0o = tile_off(mw + lm,      lq * 8);
    const int b0o = tile_off(nw + lm,      lq * 8);
    const int b1o = tile_off(nw + 16 + lm, lq * 8);

    const int rowA = tid >> 3, kcA = (tid & 7) * 4;
    const int rowB = tid >> 2, kcB = (tid & 3) * 8;
    const int aoff = tile_off(rowA, kcA);
    const int boff = tile_off(rowB, kcB);
    const unsigned short* Ap = alpha_bf + (size_t)(m0 + rowA) * PP + kcA;
    const unsigned short* Bp = ET + (size_t)(n0 + rowB) * PP + kcB;

    floatx4 acc[2];
    const floatx4 zero = {0.f, 0.f, 0.f, 0.f};
    acc[0] = zero; acc[1] = zero;

    uint2 pa = *(const uint2*)Ap;
    uint4 pb = *(const uint4*)Bp;

    for (int k0 = 0; k0 < K; k0 += 32) {
        const int buf = (k0 >> 5) & 1;
        *(uint2*)&As[buf][aoff] = pa;
        *(uint4*)&Bs[buf][boff] = pb;
        __syncthreads();
        if (k0 + 32 < K) {
            pa = *(const uint2*)(Ap + k0 + 32);
            pb = *(const uint4*)(Bp + k0 + 32);
        }
        LdsVec fa, fb0, fb1;
        fa.u  = *(const uint4*)&As[buf][a0o];
        fb0.u = *(const uint4*)&Bs[buf][b0o];
        fb1.u = *(const uint4*)&Bs[buf][b1o];
        acc[0] = __builtin_amdgcn_mfma_f32_16x16x32_bf16(fa.v, fb0.v, acc[0], 0, 0, 0);
        acc[1] = __builtin_amdgcn_mfma_f32_16x16x32_bf16(fa.v, fb1.v, acc[1], 0, 0, 0);
    }

    #pragma unroll
    for (int s = 0; s < 2; ++s) {
        const int col = n0 + nw + s * 16 + lm;
        #pragma unroll
        for (int r = 0; r < 4; ++r)
            awe[(size_t)(m0 + mw + lq * 4 + r) * ENC + col] = acc[s][r];
    }
}

// ---------------------------------------------------------------------------
extern "C" void kernel_launch(void* const* d_in, const int* in_sizes, int n_in,
                              void* d_out, int out_size, void* d_ws, size_t ws_size,
                              hipStream_t stream)
{
    const float* encoder = (const float*)d_in[0];
    const float* dec     = (const float*)d_in[1];
    const float* lang    = (const float*)d_in[2];
    const float* We      = (const float*)d_in[3];
    const float* be      = (const float*)d_in[4];
    const float* Wt      = (const float*)d_in[5];
    const float* bt      = (const float*)d_in[6];
    const float* Wl      = (const float*)d_in[7];
    const float* bl      = (const float*)d_in[8];
    const float* Wf      = (const float*)d_in[9];
    // d_in[10] = bf: uniform over p -> cancels in softmax.

    unsigned short* uT  = (unsigned short*)d_ws;           // [256][1024] bf16
    unsigned short* v1T = uT  + ATT * NN;
    unsigned short* v2T = v1T + ATT * NN;
    float* attp = (float*)(v2T + ATT * NN);                // [2][1024][1024] fp32
    unsigned short* alpha_bf = (unsigned short*)(attp + 2 * (size_t)NN * PP);
    unsigned short* ET       = alpha_bf + (size_t)NN * PP; // [512][1024] bf16

    float* awe   = (float*)d_out;                          // (1024, 512)
    float* alpha = (float*)d_out + NN * ENC;               // (1024, 1024)

    mfma_uv<<<dim3(4, 16, 4), 256, 0, stream>>>(
        encoder, We, be, dec, Wt, bt, lang, Wl, bl, uT, v1T, v2T, ET);
    att_fused<<<dim3(PP / 128, NN / 64, 2), 256, 0, stream>>>(uT, v1T, v2T, Wf, attp);
    softmax_rows<<<dim3(NN / 4), 256, 0, stream>>>(attp, alpha, alpha_bf);
    mfma_awe<<<dim3(ENC / 64, NN / 32), 256, 0, stream>>>(alpha_bf, ET, awe);
}